// Round 22
// baseline (1044.054 us; speedup 1.0000x reference)
//
#include <hip/hip_runtime.h>
#include <hip/hip_bf16.h>
#include <cstdint>

#define NB 16
#define NC 32
#define T0 16384
#define NL 30
#define SKC 256
#define TF 13315
#define WGRP 192          // final cols per group block
#define XBC 320           // staged col capacity in group LDS (Cin max 319)
#define XBS 20            // x LDS col stride in u32 (80B, 16B-aligned for b128)

typedef _Float16 f16;
typedef _Float16 f16x2 __attribute__((ext_vector_type(2)));
typedef _Float16 f16x8 __attribute__((ext_vector_type(8)));
typedef float f32x4 __attribute__((ext_vector_type(4)));
typedef uint32_t u32;

#define MFMA16(a,b,c) __builtin_amdgcn_mfma_f32_16x16x32_f16(a,b,c,0,0,0)

#define SCF (-2.88539008f)   // -2*log2(e): ef = e^-2f = 2^(SCF*f)
#define SCG (-1.44269504f)   // -log2(e):   eg = e^-g  = 2^(SCG*g)
#define CLF 86.6f
#define CLG 43.3f

__device__ __forceinline__ float frcp(float x){
#if __has_builtin(__builtin_amdgcn_rcpf)
  return __builtin_amdgcn_rcpf(x);
#else
  return 1.f/x;
#endif
}
__device__ __forceinline__ float fexp2(float x){
#if __has_builtin(__builtin_amdgcn_exp2f)
  return __builtin_amdgcn_exp2f(x);
#else
  return exp2f(x);
#endif
}
__device__ __forceinline__ float clampf(float x, float c){
#if __has_builtin(__builtin_amdgcn_fmed3f)
  return __builtin_amdgcn_fmed3f(x, -c, c);
#else
  return fminf(fmaxf(x, -c), c);
#endif
}
__device__ __forceinline__ u32 pk2(float x, float y){
#if __has_builtin(__builtin_amdgcn_cvt_pkrtz)
  return __builtin_bit_cast(u32, __builtin_amdgcn_cvt_pkrtz(x, y));
#else
  f16x2 r; r.x = (f16)x; r.y = (f16)y;
  return __builtin_bit_cast(u32, r);
#endif
}
__device__ __forceinline__ u32 pkadd(u32 a, u32 b){
  f16x2 s = __builtin_bit_cast(f16x2, a) + __builtin_bit_cast(f16x2, b);
  return __builtin_bit_cast(u32, s);
}
// async global->LDS, 16B per lane: dst = uniform base + lane*16, src per-lane
#if __has_builtin(__builtin_amdgcn_global_load_lds)
#define HAVE_GLL 1
__device__ __forceinline__ void gll16(const void* g, void* l){
  __builtin_amdgcn_global_load_lds(
      (const __attribute__((address_space(1))) u32*)g,
      (__attribute__((address_space(3))) u32*)l, 16, 0, 0);
}
#else
#define HAVE_GLL 0
#endif
// z-stack fragment layout per (b, 64t-block): [tt=(t>>4)&3][lane=q*16+(t&15)][8]
// Channel order within an octet is sigma-permuted; weights match (prep).
__device__ __forceinline__ size_t zfrag_off(int lz, int q){
  return (size_t)(lz & ~63)*NC + (size_t)(((lz>>4)&3)*512 + (q*16 + (lz&15))*8);
}
// sigma(8q+j) = j<4 ? 4q+j : 12+4q+j  (bijective on 0..31)
__device__ __forceinline__ int sigma_co(int q, int j){
  return (j < 4) ? (4*q + j) : (12 + 4*q + j);
}

// ---------------- prep: weights -> f16 fragment order / tap-major layouts ---
__global__ __launch_bounds__(256) void prep3(
    const float* __restrict__ sw, const float* __restrict__ e1w,
    const float* __restrict__ e2w, const float* __restrict__ fw,
    const float* __restrict__ gw, const float* __restrict__ rw,
    f16* __restrict__ wsk, f16* __restrict__ e1f, f16* __restrict__ e2f,
    f16* __restrict__ fgpf, f16* __restrict__ ggpf, u32* __restrict__ rwp){
  int idx = blockIdx.x*256 + threadIdx.x;
  if (idx < 30720){                    // skip frag [i][mt][lane][8], k sigma-perm
    int lane = idx & 63, mt = (idx>>6)&15, i = idx>>10;
    int m = mt*16 + (lane&15);
    int q = lane >> 4;
    const float* s = sw + ((size_t)i*SKC + m)*NC;
    f16* dp = wsk + (size_t)idx*8;
    #pragma unroll
    for (int j=0;j<8;j++) dp[j] = (f16)s[sigma_co(q, j)];
  } else if (idx < 38912){             // e1 frag: [ks][mt][lane][8]
    int j2 = idx - 30720;
    int lane = j2&63, mt = (j2>>6)&15, ks = j2>>10;
    int m = mt*16 + (lane&15);
    int k = ks*32 + (lane>>4)*8;
    const float* s = e1w + (size_t)m*SKC + k;
    f16* dp = e1f + (size_t)j2*8;
    #pragma unroll
    for (int j=0;j<8;j++) dp[j] = (f16)s[j];
  } else if (idx < 47104){             // e2 frag
    int j2 = idx - 38912;
    int lane = j2&63, mt = (j2>>6)&15, ks = j2>>10;
    int m = mt*16 + (lane&15);
    int k = ks*32 + (lane>>4)*8;
    const float* s = e2w + (size_t)m*SKC + k;
    f16* dp = e2f + (size_t)j2*8;
    #pragma unroll
    for (int j=0;j<8;j++) dp[j] = (f16)s[j];
  } else if (idx < 77824){             // filt, exp2-scaled, tap-major [co][tap][ci]
    int j2 = idx - 47104;
    const float* s = fw + (size_t)j2*2;
    size_t base = (size_t)(j2 >> 5) * 64;
    int ci = j2 & 31;
    fgpf[base + ci]      = (f16)(s[0]*SCF);
    fgpf[base + 32 + ci] = (f16)(s[1]*SCF);
  } else if (idx < 108544){            // gate, exp2-scaled, tap-major
    int j2 = idx - 77824;
    const float* s = gw + (size_t)j2*2;
    size_t base = (size_t)(j2 >> 5) * 64;
    int ci = j2 & 31;
    ggpf[base + ci]      = (f16)(s[0]*SCG);
    ggpf[base + 32 + ci] = (f16)(s[1]*SCG);
  } else if (idx < 123904){            // res rows, k sigma-permuted
    int j2 = idx - 108544;
    int i = j2 >> 9, c = (j2>>4)&31, pj = j2&15;
    const float* s = rw + ((size_t)i*NC + c)*NC;
    int q = pj >> 2, j0 = (2*pj) & 7;
    int c0 = sigma_co(q, j0);          // sigma(p0); sigma(p0+1)=c0+1 (same branch)
    f16x2 p; p.x = (f16)s[c0]; p.y = (f16)s[c0+1];
    rwp[j2] = __builtin_bit_cast(u32, p);
  }
}

// ---------------- per-layer weight fragments ----------------
struct LW { f16x8 af[4]; f16x8 ag[4]; f16x8 ar[2]; };
__device__ __forceinline__ void lw_load(LW& w, const f16* __restrict__ fp,
    const f16* __restrict__ gp, const u32* __restrict__ rp, int lane){
  int m = lane & 15, q8 = (lane >> 4) * 8, q4 = (lane >> 4) * 4;
  #pragma unroll
  for (int mh = 0; mh < 2; mh++){
    #pragma unroll
    for (int tap = 0; tap < 2; tap++){
      w.af[mh*2+tap] = *(const f16x8*)&fp[((mh*16+m)*2+tap)*32 + q8];
      w.ag[mh*2+tap] = *(const f16x8*)&gp[((mh*16+m)*2+tap)*32 + q8];
    }
    w.ar[mh] = *(const f16x8*)&rp[(mh*16+m)*16 + q4];
  }
}

// ------- 16-col tile engine: tap-major, sigma-permuted res k (NO shuffles) --
__device__ __forceinline__ void tile_core(const LW& w,
    uint4 a, uint4 b, uint2 rb0, uint2 rb1,
    uint4& zfrag, uint2& xo0, uint2& xo1){
  f16x8 A  = __builtin_bit_cast(f16x8, a);
  f16x8 Bt = __builtin_bit_cast(f16x8, b);
  f32x4 z4 = {0.f,0.f,0.f,0.f};
  f32x4 fa0 = MFMA16(w.af[0], A, z4); fa0 = MFMA16(w.af[1], Bt, fa0);
  f32x4 fa1 = MFMA16(w.af[2], A, z4); fa1 = MFMA16(w.af[3], Bt, fa1);
  f32x4 ga0 = MFMA16(w.ag[0], A, z4); ga0 = MFMA16(w.ag[1], Bt, ga0);
  f32x4 ga1 = MFMA16(w.ag[2], A, z4); ga1 = MFMA16(w.ag[3], Bt, ga1);
  u32 zq[4];
  #pragma unroll
  for (int mh = 0; mh < 2; mh++){
    f32x4 fv = mh ? fa1 : fa0;
    f32x4 gv = mh ? ga1 : ga0;
    float zz[4];
    #pragma unroll
    for (int r = 0; r < 4; r++){
      float t = fexp2(clampf(fv[r], CLF));
      float u = fexp2(clampf(gv[r], CLG));
      zz[r] = (1.f - t) * frcp((1.f + t) * (1.f + u));
    }
    zq[mh*2+0] = pk2(zz[0], zz[1]);
    zq[mh*2+1] = pk2(zz[2], zz[3]);
  }
  // lane (t,q)'s own zq IS the sigma-permuted B-frag (k-octet q) for col t
  zfrag = make_uint4(zq[0], zq[1], zq[2], zq[3]);
  f16x8 zB = __builtin_bit_cast(f16x8, zfrag);
  f32x4 r0 = MFMA16(w.ar[0], zB, z4);
  f32x4 r1 = MFMA16(w.ar[1], zB, z4);
  xo0.x = pkadd(pk2(r0[0], r0[1]), rb0.x);
  xo0.y = pkadd(pk2(r0[2], r0[3]), rb0.y);
  xo1.x = pkadd(pk2(r1[0], r1[1]), rb1.x);
  xo1.y = pkadd(pk2(r1[2], r1[3]), rb1.y);
}

// ---------------- fused 7-layer group (d=1..64), weights pipelined ----------
struct Trim7 { int t[7]; };

__global__ __launch_bounds__(256, 3) void group7m(
    const f16* __restrict__ xin, const float* __restrict__ y,
    const float* __restrict__ cw, const float* __restrict__ cb, int tc0,
    f16* __restrict__ xout, f16* __restrict__ zbase, int g0,
    int Lfinal, int TcAct, int zrows, int xpb,
    const f16* __restrict__ fgpf, const f16* __restrict__ ggpf,
    const u32* __restrict__ rwp, Trim7 trims){
  __shared__ u32 xb[2][XBC*XBS];    // 51,200 B -> 3 blocks/CU
  int tid = threadIdx.x, b = blockIdx.y, o0 = blockIdx.x*WGRP;
  int lane = tid & 63, widx = tid >> 6;
  int Cf = Lfinal - o0; if (Cf > WGRP) Cf = WGRP;
  int Cin = Cf + 127;               // <= 319
  for (int p = tid; p < Cin; p += 256){
    u32* dst = &xb[0][p*XBS];
    if (y != nullptr){
      float yv = y[(size_t)b*T0 + tc0 + o0 + p];
      #pragma unroll
      for (int j = 0; j < 16; j++)
        dst[j] = pk2(fmaf(cw[2*j], yv, cb[2*j]), fmaf(cw[2*j+1], yv, cb[2*j+1]));
    } else {
      const uint4* src = (const uint4*)(xin + ((size_t)b*xpb + o0 + p)*NC);
      uint4* d4 = (uint4*)dst;
      d4[0]=src[0]; d4[1]=src[1]; d4[2]=src[2]; d4[3]=src[3];
    }
  }
  __syncthreads();
  int cur = 0;
  int tl = lane & 15, q = lane >> 4;
  size_t zlayer = (size_t)512*zrows;       // f16 per layer (NB*zrows*NC)
  LW w;
  lw_load(w, fgpf + (size_t)g0*2048, ggpf + (size_t)g0*2048,
          rwp + (size_t)g0*512, lane);
  #pragma unroll 1
  for (int li = 0; li < 7; li++){
    int d = 1 << li;
    int count = Cf + 128 - (2 << li);
    LW wn;
    if (li < 6)
      lw_load(wn, fgpf + (size_t)(g0+li+1)*2048, ggpf + (size_t)(g0+li+1)*2048,
              rwp + (size_t)(g0+li+1)*512, lane);
    f16* zl = zbase + (size_t)(g0+li)*zlayer + (size_t)b*zrows*NC;
    int trim = trims.t[li];
    int ntiles = (count + 15) >> 4;
    for (int ti = widx; ti < ntiles; ti += 4){
      int c = ti*16 + tl;
      const u32* xc = &xb[cur][c*XBS];
      const u32* xd = &xb[cur][(c+d)*XBS];
      uint4 a  = *(const uint4*)&xc[q*4];
      uint4 b4 = *(const uint4*)&xd[q*4];
      uint2 rb0 = *(const uint2*)&xd[q*2];
      uint2 rb1 = *(const uint2*)&xd[8 + q*2];
      uint4 zf; uint2 xo0, xo1;
      tile_core(w, a, b4, rb0, rb1, zf, xo0, xo1);
      u32* xn = &xb[cur^1][c*XBS];
      *(uint2*)&xn[q*2] = xo0;
      *(uint2*)&xn[8 + q*2] = xo1;
      int lz = o0 + c - trim;
      if (c < count && lz >= 0 && lz < TcAct)
        *(uint4*)(zl + zfrag_off(lz, q)) = zf;
    }
    __syncthreads();
    if (li < 6) w = wn;
    cur ^= 1;
  }
  for (int p = tid; p < Cf; p += 256){
    const uint4* s4 = (const uint4*)&xb[cur][p*XBS];
    uint4* dd = (uint4*)(xout + ((size_t)b*xpb + o0 + p)*NC);
    dd[0]=s4[0]; dd[1]=s4[1]; dd[2]=s4[2]; dd[3]=s4[3];
  }
}

// -------- single dilated layer (d=128/256/512), 2 tiles/wave, no LDS --------
__global__ __launch_bounds__(256, 3) void singlem(
    const f16* __restrict__ xin, f16* __restrict__ xout, f16* __restrict__ zl,
    const f16* __restrict__ fp, const f16* __restrict__ gp,
    const u32* __restrict__ rp, int Tout, int d, int trim, int TcAct,
    int zrows, int xpb){
  int tid = threadIdx.x, b = blockIdx.y;
  int lane = tid & 63, widx = tid >> 6;
  int t0A = (blockIdx.x*8 + widx*2) * 16;
  if (t0A >= Tout) return;
  int haveB = (t0A + 16) < Tout;
  LW w;
  lw_load(w, fp, gp, rp, lane);
  int tl = lane & 15, q = lane >> 4;
  const f16* xbase = xin + (size_t)b*xpb*NC;
  int cA = t0A + tl;
  const f16* xcA = xbase + (size_t)cA*NC;
  const f16* xdA = xcA + (size_t)d*NC;
  uint4 aA  = *(const uint4*)(xcA + q*8);
  uint4 bA  = *(const uint4*)(xdA + q*8);
  uint2 r0A = *(const uint2*)(xdA + q*4);
  uint2 r1A = *(const uint2*)(xdA + 16 + q*4);
  int cB = cA + 16;
  const f16* xcB = xbase + (size_t)cB*NC;
  const f16* xdB = xcB + (size_t)d*NC;
  uint4 aB  = *(const uint4*)(xcB + q*8);
  uint4 bB  = *(const uint4*)(xdB + q*8);
  uint2 r0B = *(const uint2*)(xdB + q*4);
  uint2 r1B = *(const uint2*)(xdB + 16 + q*4);

  uint4 zfA, zfB; uint2 xo0A, xo1A, xo0B, xo1B;
  tile_core(w, aA, bA, r0A, r1A, zfA, xo0A, xo1A);
  tile_core(w, aB, bB, r0B, r1B, zfB, xo0B, xo1B);

  if (cA < Tout){
    f16* xoc = xout + ((size_t)b*xpb + cA)*NC;
    *(uint2*)(xoc + q*4) = xo0A;
    *(uint2*)(xoc + 16 + q*4) = xo1A;
  }
  if (haveB && cB < Tout){
    f16* xoc = xout + ((size_t)b*xpb + cB)*NC;
    *(uint2*)(xoc + q*4) = xo0B;
    *(uint2*)(xoc + 16 + q*4) = xo1B;
  }
  f16* zlb = zl + (size_t)b*zrows*NC;
  {
    int lz = cA - trim;
    if (cA < Tout && lz >= 0 && lz < TcAct)
      *(uint4*)(zlb + zfrag_off(lz, q)) = zfA;
  }
  if (haveB){
    int lz = cB - trim;
    if (cB < Tout && lz >= 0 && lz < TcAct)
      *(uint4*)(zlb + zfrag_off(lz, q)) = zfB;
  }
}

// ------- fused skip(K=960) -> relu -> end1 -> relu -> end2, write f32 -------
// 512 threads / 8 waves, 2 M-tiles per wave: acc = 32 VGPR/thread (no spill).
// z staged via async global_load_lds into 2-half x 3-layer ring; 1 barrier
// per 3 layers; loads issued a full group early.  [r16 best-known config]
__global__ __launch_bounds__(512, 2) void skipend(
    const f16* __restrict__ zbase,
    const f16* __restrict__ wsk, const f16* __restrict__ e1f,
    const float* __restrict__ e1b, const f16* __restrict__ e2f,
    const float* __restrict__ e2b, float* __restrict__ out,
    int tc0, int TcAct, int zrows){
  __shared__ u32 smem[64*132];        // 33,792 B; ring = first 24 KB
  int tid = threadIdx.x, b = blockIdx.y, t0 = blockIdx.x*64;
  int w = tid>>6, lane = tid&63;      // 8 waves
  int tl = lane & 15;
  int q  = lane >> 4;
  const uint4* wsk4 = (const uint4*)wsk;
  const uint4* e1f4 = (const uint4*)e1f;
  const uint4* e2f4 = (const uint4*)e2f;
  size_t zstepf = (size_t)512*zrows;  // f16 per layer
  const f16* zsrcb = zbase + ((size_t)b*zrows + t0)*NC;

  f32x4 acc[2][4];
  #pragma unroll
  for (int j=0;j<2;j++)
    #pragma unroll
    for (int tt=0;tt<4;tt++) acc[j][tt] = f32x4{0.f,0.f,0.f,0.f};

  // stage 3 layers (12 slots of 64 frags) into ring half h
  auto stage = [&](int half, int lbase){
    #pragma unroll 1
    for (int s = w; s < 12; s += 8){
      int ks = s>>2, sq = s&3;
#if HAVE_GLL
      gll16(zsrcb + (size_t)(lbase+ks)*zstepf + (size_t)(sq*64+lane)*8,
            smem + (size_t)half*3072 + ks*1024 + sq*256);
#else
      uint4 v = *(const uint4*)(zsrcb + (size_t)(lbase+ks)*zstepf +
                                (size_t)(sq*64+lane)*8);
      *(uint4*)(smem + (size_t)half*3072 + ks*1024 + sq*256 + lane*4) = v;
#endif
    }
  };

  stage(0, 0);
  __syncthreads();
  #pragma unroll 1
  for (int g = 0; g < 10; g++){
    if (g < 9) stage((g+1)&1, 3*(g+1));
    const uint4* zr = (const uint4*)(smem + (size_t)(g&1)*3072);
    int lbase = g*3;
    #pragma unroll
    for (int k = 0; k < 3; k++){
      uint4 aw0 = wsk4[(size_t)(lbase+k)*1024 + (w*2+0)*64 + lane];
      uint4 aw1 = wsk4[(size_t)(lbase+k)*1024 + (w*2+1)*64 + lane];
      f16x8 zb0 = *(const f16x8*)&zr[k*256 + 0*64 + lane];
      f16x8 zb1 = *(const f16x8*)&zr[k*256 + 1*64 + lane];
      f16x8 zb2 = *(const f16x8*)&zr[k*256 + 2*64 + lane];
      f16x8 zb3 = *(const f16x8*)&zr[k*256 + 3*64 + lane];
      f16x8 a0 = __builtin_bit_cast(f16x8, aw0);
      f16x8 a1 = __builtin_bit_cast(f16x8, aw1);
      acc[0][0] = MFMA16(a0, zb0, acc[0][0]);
      acc[0][1] = MFMA16(a0, zb1, acc[0][1]);
      acc[0][2] = MFMA16(a0, zb2, acc[0][2]);
      acc[0][3] = MFMA16(a0, zb3, acc[0][3]);
      acc[1][0] = MFMA16(a1, zb0, acc[1][0]);
      acc[1][1] = MFMA16(a1, zb1, acc[1][1]);
      acc[1][2] = MFMA16(a1, zb2, acc[1][2]);
      acc[1][3] = MFMA16(a1, zb3, acc[1][3]);
    }
    __syncthreads();
  }
  // phase2: relu(skip) -> sA [t][264 f16]
  int rq = q*4;
  #pragma unroll
  for (int j=0;j<2;j++){
    int c0 = (w*2+j)*16 + rq;
    #pragma unroll
    for (int tt=0;tt<4;tt++){
      int t = tt*16 + tl;
      u32 p0 = pk2(fmaxf(acc[j][tt][0],0.f), fmaxf(acc[j][tt][1],0.f));
      u32 p1 = pk2(fmaxf(acc[j][tt][2],0.f), fmaxf(acc[j][tt][3],0.f));
      *(uint2*)&smem[t*132 + (c0>>1)] = make_uint2(p0, p1);
    }
  }
  __syncthreads();
  // phase3: end1
  #pragma unroll
  for (int j=0;j<2;j++)
    #pragma unroll
    for (int tt=0;tt<4;tt++) acc[j][tt] = f32x4{0.f,0.f,0.f,0.f};
  #pragma unroll
  for (int ks=0;ks<8;ks++){
    f16x8 zb[4];
    #pragma unroll
    for (int tt=0;tt<4;tt++)
      zb[tt] = *(const f16x8*)&smem[(tt*16+tl)*132 + ks*16 + q*4];
    #pragma unroll
    for (int j=0;j<2;j++){
      f16x8 a = __builtin_bit_cast(f16x8, e1f4[(size_t)(ks*16 + w*2+j)*64 + lane]);
      #pragma unroll
      for (int tt=0;tt<4;tt++)
        acc[j][tt] = MFMA16(a, zb[tt], acc[j][tt]);
    }
  }
  __syncthreads();     // all sA reads done; safe to overwrite with sB
  #pragma unroll
  for (int j=0;j<2;j++){
    int c0 = (w*2+j)*16 + rq;
    float4 bv = *(const float4*)&e1b[c0];
    #pragma unroll
    for (int tt=0;tt<4;tt++){
      int t = tt*16 + tl;
      u32 p0 = pk2(fmaxf(acc[j][tt][0]+bv.x,0.f), fmaxf(acc[j][tt][1]+bv.y,0.f));
      u32 p1 = pk2(fmaxf(acc[j][tt][2]+bv.z,0.f), fmaxf(acc[j][tt][3]+bv.w,0.f));
      *(uint2*)&smem[t*132 + (c0>>1)] = make_uint2(p0, p1);
    }
  }
  __syncthreads();
  // phase4: end2 + final write
  #pragma unroll
  for (int j=0;j<2;j++)
    #pragma unroll
    for (int tt=0;tt<4;tt++) acc[j][tt] = f32x4{0.f,0.f,0.f,0.f};
  #pragma unroll
  for (int ks=0;ks<8;ks++){
    f16x8 zb[4];
    #pragma unroll
    for (int tt=0;tt<4;tt++)
      zb[tt] = *(const f16x8*)&smem[(tt*16+tl)*132 + ks*16 + q*4];
    #pragma unroll
    for (int j=0;j<2;j++){
      f16x8 a = __builtin_bit_cast(f16x8, e2f4[(size_t)(ks*16 + w*2+j)*64 + lane]);
      #pragma unroll
      for (int tt=0;tt<4;tt++)
        acc[j][tt] = MFMA16(a, zb[tt], acc[j][tt]);
    }
  }
  #pragma unroll
  for (int j=0;j<2;j++){
    int c0 = (w*2+j)*16 + rq;
    float4 bv = *(const float4*)&e2b[c0];
    #pragma unroll
    for (int tt=0;tt<4;tt++){
      int t = tt*16 + tl;
      if (t0 + t < TcAct){
        float* op = out + ((size_t)b*SKC + c0)*TF + tc0 + t0 + t;
        op[0*TF] = acc[j][tt][0] + bv.x;
        op[1*TF] = acc[j][tt][1] + bv.y;
        op[2*TF] = acc[j][tt][2] + bv.z;
        op[3*TF] = acc[j][tt][3] + bv.w;
      }
    }
  }
}

extern "C" void kernel_launch(void* const* d_in, const int* in_sizes, int n_in,
                              void* d_out, int out_size, void* d_ws, size_t ws_size,
                              hipStream_t stream) {
  (void)in_sizes; (void)n_in; (void)out_size;
  const float* y   = (const float*)d_in[0];
  const float* cw  = (const float*)d_in[1];
  const float* cb  = (const float*)d_in[2];
  const float* fw  = (const float*)d_in[3];
  const float* gw  = (const float*)d_in[4];
  const float* rw  = (const float*)d_in[5];
  const float* sw  = (const float*)d_in[6];
  const float* e1w = (const float*)d_in[7];
  const float* e1b = (const float*)d_in[8];
  const float* e2w = (const float*)d_in[9];
  const float* e2b = (const float*)d_in[10];
  float* out = (float*)d_out;
  char* ws = (char*)d_ws;

  // adaptive chunking: fewest chunks whose buffers fit ws AND whose z-stack
  // stays <= 112 MB so it remains Infinity-Cache(L3)-resident between the
  // producer writes and the skipend reads.
  const size_t fixedW = 1060864;
  const size_t ZCAP = (size_t)112 << 20;
  int TCc = 0, xpb = 0;
  for (int c = 1; c <= 6; c++){
    int tcc = (((TF + c - 1)/c) + 63) & ~63;
    int xp  = tcc + 3264;
    size_t zbytes = (size_t)NL*512*(size_t)tcc*2;
    size_t need = fixedW + 2*(size_t)xp*1024 + zbytes;
    if (need <= ws_size && zbytes <= ZCAP){ TCc = tcc; xpb = xp; break; }
  }
  if (!TCc){ TCc = 2240; xpb = 2240 + 3264; }   // 81.5 MB, always fits

  f16* wsk   = (f16*)(ws);                      //   491,520
  f16* e1f   = (f16*)(ws +   491520);           //   131,072
  f16* e2f   = (f16*)(ws +   622592);           //   131,072
  f16* fgpf  = (f16*)(ws +  753664);            //   122,880
  f16* ggpf  = (f16*)(ws +  876544);            //   122,880
  u32* rwp   = (u32*)(ws +  999424);            //    61,440
  f16* xpA   = (f16*)(ws + fixedW);
  f16* xpB   = (f16*)(ws + fixedW + (size_t)xpb*1024);
  f16* zstack = (f16*)(ws + fixedW + 2*(size_t)xpb*1024);

  int S[NL+1]; S[NL] = 0;
  for (int i = NL-1; i >= 0; i--) S[i] = S[i+1] + (1 << (i % 10));

  prep3<<<dim3(484), 256, 0, stream>>>(sw, e1w, e2w, fw, gw, rw,
                                       wsk, e1f, e2f, fgpf, ggpf, rwp);

  f16* bufs[2] = {xpA, xpB};
  for (int tc0 = 0; tc0 < TF; tc0 += TCc){
    int TcAct = TF - tc0; if (TcAct > TCc) TcAct = TCc;
    int cur = 0;
    for (int s = 0; s < 3; s++){
      int g0 = s*10;
      Trim7 tr;
      for (int li = 0; li < 7; li++) tr.t[li] = S[g0+li+1];
      int Lfinal = TcAct + S[g0+7];
      const f16* gin = (s == 0) ? (const f16*)nullptr : bufs[cur];
      const float* yArg = (s == 0) ? y : (const float*)nullptr;
      int nxt = (s == 0) ? 0 : (cur ^ 1);
      group7m<<<dim3((Lfinal + WGRP-1)/WGRP, NB), 256, 0, stream>>>(
          gin, yArg, cw, cb, tc0, bufs[nxt], zstack, g0, Lfinal, TcAct,
          TCc, xpb, fgpf, ggpf, rwp, tr);
      cur = nxt;
      for (int i = g0+7; i <= g0+9; i++){
        int d = 1 << (i % 10);
        int Tout = TcAct + S[i+1];
        singlem<<<dim3((Tout + 127)/128, NB), 256, 0, stream>>>(
            bufs[cur], bufs[cur^1], zstack + (size_t)i*512*TCc,
            fgpf + (size_t)i*2048, ggpf + (size_t)i*2048, rwp + (size_t)i*512,
            Tout, d, S[i+1], TcAct, TCc, xpb);
        cur ^= 1;
      }
    }
    skipend<<<dim3((TcAct + 63)/64, NB), 512, 0, stream>>>(
        zstack, wsk, e1f, e1b, e2f, e2b, out, tc0, TcAct, TCc);
  }
}

// Round 23
// 656.921 us; speedup vs baseline: 1.5893x; 1.5893x over previous
//
#include <hip/hip_runtime.h>
#include <hip/hip_bf16.h>
#include <cstdint>

#define NB 16
#define NC 32
#define T0 16384
#define NL 30
#define SKC 256
#define TF 13315
#define WGRP 192          // final cols per group block
#define XBC 320           // staged col capacity in group LDS (Cin max 319)
#define XBS 20            // x LDS col stride in u32 (80B, 16B-aligned for b128)

typedef _Float16 f16;
typedef _Float16 f16x2 __attribute__((ext_vector_type(2)));
typedef _Float16 f16x8 __attribute__((ext_vector_type(8)));
typedef float f32x4 __attribute__((ext_vector_type(4)));
typedef uint32_t u32;

#define MFMA16(a,b,c) __builtin_amdgcn_mfma_f32_16x16x32_f16(a,b,c,0,0,0)

#define SCF (-2.88539008f)   // -2*log2(e): ef = e^-2f = 2^(SCF*f)
#define SCG (-1.44269504f)   // -log2(e):   eg = e^-g  = 2^(SCG*g)
#define CLF 86.6f
#define CLG 43.3f

__device__ __forceinline__ float frcp(float x){
#if __has_builtin(__builtin_amdgcn_rcpf)
  return __builtin_amdgcn_rcpf(x);
#else
  return 1.f/x;
#endif
}
__device__ __forceinline__ float fexp2(float x){
#if __has_builtin(__builtin_amdgcn_exp2f)
  return __builtin_amdgcn_exp2f(x);
#else
  return exp2f(x);
#endif
}
__device__ __forceinline__ float clampf(float x, float c){
#if __has_builtin(__builtin_amdgcn_fmed3f)
  return __builtin_amdgcn_fmed3f(x, -c, c);
#else
  return fminf(fmaxf(x, -c), c);
#endif
}
__device__ __forceinline__ u32 pk2(float x, float y){
#if __has_builtin(__builtin_amdgcn_cvt_pkrtz)
  return __builtin_bit_cast(u32, __builtin_amdgcn_cvt_pkrtz(x, y));
#else
  f16x2 r; r.x = (f16)x; r.y = (f16)y;
  return __builtin_bit_cast(u32, r);
#endif
}
__device__ __forceinline__ u32 pkadd(u32 a, u32 b){
  f16x2 s = __builtin_bit_cast(f16x2, a) + __builtin_bit_cast(f16x2, b);
  return __builtin_bit_cast(u32, s);
}
// async global->LDS, 16B per lane: dst = uniform base + lane*16, src per-lane
#if __has_builtin(__builtin_amdgcn_global_load_lds)
#define HAVE_GLL 1
__device__ __forceinline__ void gll16(const void* g, void* l){
  __builtin_amdgcn_global_load_lds(
      (const __attribute__((address_space(1))) u32*)g,
      (__attribute__((address_space(3))) u32*)l, 16, 0, 0);
}
#else
#define HAVE_GLL 0
#endif
// z-stack fragment layout per (b, 64t-block): [tt=(t>>4)&3][lane=q*16+(t&15)][8]
// Channel order within an octet is sigma-permuted; weights match (prep).
__device__ __forceinline__ size_t zfrag_off(int lz, int q){
  return (size_t)(lz & ~63)*NC + (size_t)(((lz>>4)&3)*512 + (q*16 + (lz&15))*8);
}
// sigma(8q+j) = j<4 ? 4q+j : 12+4q+j  (bijective on 0..31)
__device__ __forceinline__ int sigma_co(int q, int j){
  return (j < 4) ? (4*q + j) : (12 + 4*q + j);
}

// ---------------- prep: weights -> f16 fragment order / tap-major layouts ---
__global__ __launch_bounds__(256) void prep3(
    const float* __restrict__ sw, const float* __restrict__ e1w,
    const float* __restrict__ e2w, const float* __restrict__ fw,
    const float* __restrict__ gw, const float* __restrict__ rw,
    f16* __restrict__ wsk, f16* __restrict__ e1f, f16* __restrict__ e2f,
    f16* __restrict__ fgpf, f16* __restrict__ ggpf, u32* __restrict__ rwp){
  int idx = blockIdx.x*256 + threadIdx.x;
  if (idx < 30720){                    // skip frag [i][mt][lane][8], k sigma-perm
    int lane = idx & 63, mt = (idx>>6)&15, i = idx>>10;
    int m = mt*16 + (lane&15);
    int q = lane >> 4;
    const float* s = sw + ((size_t)i*SKC + m)*NC;
    f16* dp = wsk + (size_t)idx*8;
    #pragma unroll
    for (int j=0;j<8;j++) dp[j] = (f16)s[sigma_co(q, j)];
  } else if (idx < 38912){             // e1 frag: [ks][mt][lane][8]
    int j2 = idx - 30720;
    int lane = j2&63, mt = (j2>>6)&15, ks = j2>>10;
    int m = mt*16 + (lane&15);
    int k = ks*32 + (lane>>4)*8;
    const float* s = e1w + (size_t)m*SKC + k;
    f16* dp = e1f + (size_t)j2*8;
    #pragma unroll
    for (int j=0;j<8;j++) dp[j] = (f16)s[j];
  } else if (idx < 47104){             // e2 frag
    int j2 = idx - 38912;
    int lane = j2&63, mt = (j2>>6)&15, ks = j2>>10;
    int m = mt*16 + (lane&15);
    int k = ks*32 + (lane>>4)*8;
    const float* s = e2w + (size_t)m*SKC + k;
    f16* dp = e2f + (size_t)j2*8;
    #pragma unroll
    for (int j=0;j<8;j++) dp[j] = (f16)s[j];
  } else if (idx < 77824){             // filt, exp2-scaled, tap-major [co][tap][ci]
    int j2 = idx - 47104;
    const float* s = fw + (size_t)j2*2;
    size_t base = (size_t)(j2 >> 5) * 64;
    int ci = j2 & 31;
    fgpf[base + ci]      = (f16)(s[0]*SCF);
    fgpf[base + 32 + ci] = (f16)(s[1]*SCF);
  } else if (idx < 108544){            // gate, exp2-scaled, tap-major
    int j2 = idx - 77824;
    const float* s = gw + (size_t)j2*2;
    size_t base = (size_t)(j2 >> 5) * 64;
    int ci = j2 & 31;
    ggpf[base + ci]      = (f16)(s[0]*SCG);
    ggpf[base + 32 + ci] = (f16)(s[1]*SCG);
  } else if (idx < 123904){            // res rows, k sigma-permuted
    int j2 = idx - 108544;
    int i = j2 >> 9, c = (j2>>4)&31, pj = j2&15;
    const float* s = rw + ((size_t)i*NC + c)*NC;
    int q = pj >> 2, j0 = (2*pj) & 7;
    int c0 = sigma_co(q, j0);          // sigma(p0); sigma(p0+1)=c0+1 (same branch)
    f16x2 p; p.x = (f16)s[c0]; p.y = (f16)s[c0+1];
    rwp[j2] = __builtin_bit_cast(u32, p);
  }
}

// ---------------- per-layer weight fragments ----------------
struct LW { f16x8 af[4]; f16x8 ag[4]; f16x8 ar[2]; };
__device__ __forceinline__ void lw_load(LW& w, const f16* __restrict__ fp,
    const f16* __restrict__ gp, const u32* __restrict__ rp, int lane){
  int m = lane & 15, q8 = (lane >> 4) * 8, q4 = (lane >> 4) * 4;
  #pragma unroll
  for (int mh = 0; mh < 2; mh++){
    #pragma unroll
    for (int tap = 0; tap < 2; tap++){
      w.af[mh*2+tap] = *(const f16x8*)&fp[((mh*16+m)*2+tap)*32 + q8];
      w.ag[mh*2+tap] = *(const f16x8*)&gp[((mh*16+m)*2+tap)*32 + q8];
    }
    w.ar[mh] = *(const f16x8*)&rp[(mh*16+m)*16 + q4];
  }
}

// ------- 16-col tile engine: tap-major, sigma-permuted res k (NO shuffles) --
__device__ __forceinline__ void tile_core(const LW& w,
    uint4 a, uint4 b, uint2 rb0, uint2 rb1,
    uint4& zfrag, uint2& xo0, uint2& xo1){
  f16x8 A  = __builtin_bit_cast(f16x8, a);
  f16x8 Bt = __builtin_bit_cast(f16x8, b);
  f32x4 z4 = {0.f,0.f,0.f,0.f};
  f32x4 fa0 = MFMA16(w.af[0], A, z4); fa0 = MFMA16(w.af[1], Bt, fa0);
  f32x4 fa1 = MFMA16(w.af[2], A, z4); fa1 = MFMA16(w.af[3], Bt, fa1);
  f32x4 ga0 = MFMA16(w.ag[0], A, z4); ga0 = MFMA16(w.ag[1], Bt, ga0);
  f32x4 ga1 = MFMA16(w.ag[2], A, z4); ga1 = MFMA16(w.ag[3], Bt, ga1);
  u32 zq[4];
  #pragma unroll
  for (int mh = 0; mh < 2; mh++){
    f32x4 fv = mh ? fa1 : fa0;
    f32x4 gv = mh ? ga1 : ga0;
    float zz[4];
    #pragma unroll
    for (int r = 0; r < 4; r++){
      float t = fexp2(clampf(fv[r], CLF));
      float u = fexp2(clampf(gv[r], CLG));
      zz[r] = (1.f - t) * frcp((1.f + t) * (1.f + u));
    }
    zq[mh*2+0] = pk2(zz[0], zz[1]);
    zq[mh*2+1] = pk2(zz[2], zz[3]);
  }
  // lane (t,q)'s own zq IS the sigma-permuted B-frag (k-octet q) for col t
  zfrag = make_uint4(zq[0], zq[1], zq[2], zq[3]);
  f16x8 zB = __builtin_bit_cast(f16x8, zfrag);
  f32x4 r0 = MFMA16(w.ar[0], zB, z4);
  f32x4 r1 = MFMA16(w.ar[1], zB, z4);
  xo0.x = pkadd(pk2(r0[0], r0[1]), rb0.x);
  xo0.y = pkadd(pk2(r0[2], r0[3]), rb0.y);
  xo1.x = pkadd(pk2(r1[0], r1[1]), rb1.x);
  xo1.y = pkadd(pk2(r1[2], r1[3]), rb1.y);
}

// ---------------- fused 7-layer group (d=1..64), weights pipelined ----------
struct Trim7 { int t[7]; };

__global__ __launch_bounds__(256, 3) void group7m(
    const f16* __restrict__ xin, const float* __restrict__ y,
    const float* __restrict__ cw, const float* __restrict__ cb, int tc0,
    f16* __restrict__ xout, f16* __restrict__ zbase, int g0,
    int Lfinal, int TcAct, int zrows, int xpb,
    const f16* __restrict__ fgpf, const f16* __restrict__ ggpf,
    const u32* __restrict__ rwp, Trim7 trims){
  __shared__ u32 xb[2][XBC*XBS];    // 51,200 B -> 3 blocks/CU
  int tid = threadIdx.x, b = blockIdx.y, o0 = blockIdx.x*WGRP;
  int lane = tid & 63, widx = tid >> 6;
  int Cf = Lfinal - o0; if (Cf > WGRP) Cf = WGRP;
  int Cin = Cf + 127;               // <= 319
  for (int p = tid; p < Cin; p += 256){
    u32* dst = &xb[0][p*XBS];
    if (y != nullptr){
      float yv = y[(size_t)b*T0 + tc0 + o0 + p];
      #pragma unroll
      for (int j = 0; j < 16; j++)
        dst[j] = pk2(fmaf(cw[2*j], yv, cb[2*j]), fmaf(cw[2*j+1], yv, cb[2*j+1]));
    } else {
      const uint4* src = (const uint4*)(xin + ((size_t)b*xpb + o0 + p)*NC);
      uint4* d4 = (uint4*)dst;
      d4[0]=src[0]; d4[1]=src[1]; d4[2]=src[2]; d4[3]=src[3];
    }
  }
  __syncthreads();
  int cur = 0;
  int tl = lane & 15, q = lane >> 4;
  size_t zlayer = (size_t)512*zrows;       // f16 per layer (NB*zrows*NC)
  LW w;
  lw_load(w, fgpf + (size_t)g0*2048, ggpf + (size_t)g0*2048,
          rwp + (size_t)g0*512, lane);
  #pragma unroll 1
  for (int li = 0; li < 7; li++){
    int d = 1 << li;
    int count = Cf + 128 - (2 << li);
    LW wn;
    if (li < 6)
      lw_load(wn, fgpf + (size_t)(g0+li+1)*2048, ggpf + (size_t)(g0+li+1)*2048,
              rwp + (size_t)(g0+li+1)*512, lane);
    f16* zl = zbase + (size_t)(g0+li)*zlayer + (size_t)b*zrows*NC;
    int trim = trims.t[li];
    int ntiles = (count + 15) >> 4;
    for (int ti = widx; ti < ntiles; ti += 4){
      int c = ti*16 + tl;
      const u32* xc = &xb[cur][c*XBS];
      const u32* xd = &xb[cur][(c+d)*XBS];
      uint4 a  = *(const uint4*)&xc[q*4];
      uint4 b4 = *(const uint4*)&xd[q*4];
      uint2 rb0 = *(const uint2*)&xd[q*2];
      uint2 rb1 = *(const uint2*)&xd[8 + q*2];
      uint4 zf; uint2 xo0, xo1;
      tile_core(w, a, b4, rb0, rb1, zf, xo0, xo1);
      u32* xn = &xb[cur^1][c*XBS];
      *(uint2*)&xn[q*2] = xo0;
      *(uint2*)&xn[8 + q*2] = xo1;
      int lz = o0 + c - trim;
      if (c < count && lz >= 0 && lz < TcAct)
        *(uint4*)(zl + zfrag_off(lz, q)) = zf;
    }
    __syncthreads();
    if (li < 6) w = wn;
    cur ^= 1;
  }
  for (int p = tid; p < Cf; p += 256){
    const uint4* s4 = (const uint4*)&xb[cur][p*XBS];
    uint4* dd = (uint4*)(xout + ((size_t)b*xpb + o0 + p)*NC);
    dd[0]=s4[0]; dd[1]=s4[1]; dd[2]=s4[2]; dd[3]=s4[3];
  }
}

// -------- single dilated layer (d=128/256/512), 2 tiles/wave, no LDS --------
__global__ __launch_bounds__(256, 3) void singlem(
    const f16* __restrict__ xin, f16* __restrict__ xout, f16* __restrict__ zl,
    const f16* __restrict__ fp, const f16* __restrict__ gp,
    const u32* __restrict__ rp, int Tout, int d, int trim, int TcAct,
    int zrows, int xpb){
  int tid = threadIdx.x, b = blockIdx.y;
  int lane = tid & 63, widx = tid >> 6;
  int t0A = (blockIdx.x*8 + widx*2) * 16;
  if (t0A >= Tout) return;
  int haveB = (t0A + 16) < Tout;
  LW w;
  lw_load(w, fp, gp, rp, lane);
  int tl = lane & 15, q = lane >> 4;
  const f16* xbase = xin + (size_t)b*xpb*NC;
  int cA = t0A + tl;
  const f16* xcA = xbase + (size_t)cA*NC;
  const f16* xdA = xcA + (size_t)d*NC;
  uint4 aA  = *(const uint4*)(xcA + q*8);
  uint4 bA  = *(const uint4*)(xdA + q*8);
  uint2 r0A = *(const uint2*)(xdA + q*4);
  uint2 r1A = *(const uint2*)(xdA + 16 + q*4);
  int cB = cA + 16;
  const f16* xcB = xbase + (size_t)cB*NC;
  const f16* xdB = xcB + (size_t)d*NC;
  uint4 aB  = *(const uint4*)(xcB + q*8);
  uint4 bB  = *(const uint4*)(xdB + q*8);
  uint2 r0B = *(const uint2*)(xdB + q*4);
  uint2 r1B = *(const uint2*)(xdB + 16 + q*4);

  uint4 zfA, zfB; uint2 xo0A, xo1A, xo0B, xo1B;
  tile_core(w, aA, bA, r0A, r1A, zfA, xo0A, xo1A);
  tile_core(w, aB, bB, r0B, r1B, zfB, xo0B, xo1B);

  if (cA < Tout){
    f16* xoc = xout + ((size_t)b*xpb + cA)*NC;
    *(uint2*)(xoc + q*4) = xo0A;
    *(uint2*)(xoc + 16 + q*4) = xo1A;
  }
  if (haveB && cB < Tout){
    f16* xoc = xout + ((size_t)b*xpb + cB)*NC;
    *(uint2*)(xoc + q*4) = xo0B;
    *(uint2*)(xoc + 16 + q*4) = xo1B;
  }
  f16* zlb = zl + (size_t)b*zrows*NC;
  {
    int lz = cA - trim;
    if (cA < Tout && lz >= 0 && lz < TcAct)
      *(uint4*)(zlb + zfrag_off(lz, q)) = zfA;
  }
  if (haveB){
    int lz = cB - trim;
    if (cB < Tout && lz >= 0 && lz < TcAct)
      *(uint4*)(zlb + zfrag_off(lz, q)) = zfB;
  }
}

// ------- fused skip(K=960) -> relu -> end1 -> relu -> end2, write f32 -------
// 512 threads / 8 waves, 2 M-tiles per wave: acc = 32 VGPR/thread (no spill).
// z staged via async global_load_lds into 2-half x 3-layer ring; 1 barrier
// per 3 layers; loads issued a full group early.  [r16 best-known config]
__global__ __launch_bounds__(512, 2) void skipend(
    const f16* __restrict__ zbase,
    const f16* __restrict__ wsk, const f16* __restrict__ e1f,
    const float* __restrict__ e1b, const f16* __restrict__ e2f,
    const float* __restrict__ e2b, float* __restrict__ out,
    int tc0, int TcAct, int zrows){
  __shared__ u32 smem[64*132];        // 33,792 B; ring = first 24 KB
  int tid = threadIdx.x, b = blockIdx.y, t0 = blockIdx.x*64;
  int w = tid>>6, lane = tid&63;      // 8 waves
  int tl = lane & 15;
  int q  = lane >> 4;
  const uint4* wsk4 = (const uint4*)wsk;
  const uint4* e1f4 = (const uint4*)e1f;
  const uint4* e2f4 = (const uint4*)e2f;
  size_t zstepf = (size_t)512*zrows;  // f16 per layer
  const f16* zsrcb = zbase + ((size_t)b*zrows + t0)*NC;

  f32x4 acc[2][4];
  #pragma unroll
  for (int j=0;j<2;j++)
    #pragma unroll
    for (int tt=0;tt<4;tt++) acc[j][tt] = f32x4{0.f,0.f,0.f,0.f};

  // stage 3 layers (12 slots of 64 frags) into ring half h
  auto stage = [&](int half, int lbase){
    #pragma unroll 1
    for (int s = w; s < 12; s += 8){
      int ks = s>>2, sq = s&3;
#if HAVE_GLL
      gll16(zsrcb + (size_t)(lbase+ks)*zstepf + (size_t)(sq*64+lane)*8,
            smem + (size_t)half*3072 + ks*1024 + sq*256);
#else
      uint4 v = *(const uint4*)(zsrcb + (size_t)(lbase+ks)*zstepf +
                                (size_t)(sq*64+lane)*8);
      *(uint4*)(smem + (size_t)half*3072 + ks*1024 + sq*256 + lane*4) = v;
#endif
    }
  };

  stage(0, 0);
  __syncthreads();
  #pragma unroll 1
  for (int g = 0; g < 10; g++){
    if (g < 9) stage((g+1)&1, 3*(g+1));
    const uint4* zr = (const uint4*)(smem + (size_t)(g&1)*3072);
    int lbase = g*3;
    #pragma unroll
    for (int k = 0; k < 3; k++){
      uint4 aw0 = wsk4[(size_t)(lbase+k)*1024 + (w*2+0)*64 + lane];
      uint4 aw1 = wsk4[(size_t)(lbase+k)*1024 + (w*2+1)*64 + lane];
      f16x8 zb0 = *(const f16x8*)&zr[k*256 + 0*64 + lane];
      f16x8 zb1 = *(const f16x8*)&zr[k*256 + 1*64 + lane];
      f16x8 zb2 = *(const f16x8*)&zr[k*256 + 2*64 + lane];
      f16x8 zb3 = *(const f16x8*)&zr[k*256 + 3*64 + lane];
      f16x8 a0 = __builtin_bit_cast(f16x8, aw0);
      f16x8 a1 = __builtin_bit_cast(f16x8, aw1);
      acc[0][0] = MFMA16(a0, zb0, acc[0][0]);
      acc[0][1] = MFMA16(a0, zb1, acc[0][1]);
      acc[0][2] = MFMA16(a0, zb2, acc[0][2]);
      acc[0][3] = MFMA16(a0, zb3, acc[0][3]);
      acc[1][0] = MFMA16(a1, zb0, acc[1][0]);
      acc[1][1] = MFMA16(a1, zb1, acc[1][1]);
      acc[1][2] = MFMA16(a1, zb2, acc[1][2]);
      acc[1][3] = MFMA16(a1, zb3, acc[1][3]);
    }
    __syncthreads();
  }
  // phase2: relu(skip) -> sA [t][264 f16]
  int rq = q*4;
  #pragma unroll
  for (int j=0;j<2;j++){
    int c0 = (w*2+j)*16 + rq;
    #pragma unroll
    for (int tt=0;tt<4;tt++){
      int t = tt*16 + tl;
      u32 p0 = pk2(fmaxf(acc[j][tt][0],0.f), fmaxf(acc[j][tt][1],0.f));
      u32 p1 = pk2(fmaxf(acc[j][tt][2],0.f), fmaxf(acc[j][tt][3],0.f));
      *(uint2*)&smem[t*132 + (c0>>1)] = make_uint2(p0, p1);
    }
  }
  __syncthreads();
  // phase3: end1
  #pragma unroll
  for (int j=0;j<2;j++)
    #pragma unroll
    for (int tt=0;tt<4;tt++) acc[j][tt] = f32x4{0.f,0.f,0.f,0.f};
  #pragma unroll
  for (int ks=0;ks<8;ks++){
    f16x8 zb[4];
    #pragma unroll
    for (int tt=0;tt<4;tt++)
      zb[tt] = *(const f16x8*)&smem[(tt*16+tl)*132 + ks*16 + q*4];
    #pragma unroll
    for (int j=0;j<2;j++){
      f16x8 a = __builtin_bit_cast(f16x8, e1f4[(size_t)(ks*16 + w*2+j)*64 + lane]);
      #pragma unroll
      for (int tt=0;tt<4;tt++)
        acc[j][tt] = MFMA16(a, zb[tt], acc[j][tt]);
    }
  }
  __syncthreads();     // all sA reads done; safe to overwrite with sB
  #pragma unroll
  for (int j=0;j<2;j++){
    int c0 = (w*2+j)*16 + rq;
    float4 bv = *(const float4*)&e1b[c0];
    #pragma unroll
    for (int tt=0;tt<4;tt++){
      int t = tt*16 + tl;
      u32 p0 = pk2(fmaxf(acc[j][tt][0]+bv.x,0.f), fmaxf(acc[j][tt][1]+bv.y,0.f));
      u32 p1 = pk2(fmaxf(acc[j][tt][2]+bv.z,0.f), fmaxf(acc[j][tt][3]+bv.w,0.f));
      *(uint2*)&smem[t*132 + (c0>>1)] = make_uint2(p0, p1);
    }
  }
  __syncthreads();
  // phase4: end2 + final write
  #pragma unroll
  for (int j=0;j<2;j++)
    #pragma unroll
    for (int tt=0;tt<4;tt++) acc[j][tt] = f32x4{0.f,0.f,0.f,0.f};
  #pragma unroll
  for (int ks=0;ks<8;ks++){
    f16x8 zb[4];
    #pragma unroll
    for (int tt=0;tt<4;tt++)
      zb[tt] = *(const f16x8*)&smem[(tt*16+tl)*132 + ks*16 + q*4];
    #pragma unroll
    for (int j=0;j<2;j++){
      f16x8 a = __builtin_bit_cast(f16x8, e2f4[(size_t)(ks*16 + w*2+j)*64 + lane]);
      #pragma unroll
      for (int tt=0;tt<4;tt++)
        acc[j][tt] = MFMA16(a, zb[tt], acc[j][tt]);
    }
  }
  #pragma unroll
  for (int j=0;j<2;j++){
    int c0 = (w*2+j)*16 + rq;
    float4 bv = *(const float4*)&e2b[c0];
    #pragma unroll
    for (int tt=0;tt<4;tt++){
      int t = tt*16 + tl;
      if (t0 + t < TcAct){
        float* op = out + ((size_t)b*SKC + c0)*TF + tc0 + t0 + t;
        op[0*TF] = acc[j][tt][0] + bv.x;
        op[1*TF] = acc[j][tt][1] + bv.y;
        op[2*TF] = acc[j][tt][2] + bv.z;
        op[3*TF] = acc[j][tt][3] + bv.w;
      }
    }
  }
}

extern "C" void kernel_launch(void* const* d_in, const int* in_sizes, int n_in,
                              void* d_out, int out_size, void* d_ws, size_t ws_size,
                              hipStream_t stream) {
  (void)in_sizes; (void)n_in; (void)out_size;
  const float* y   = (const float*)d_in[0];
  const float* cw  = (const float*)d_in[1];
  const float* cb  = (const float*)d_in[2];
  const float* fw  = (const float*)d_in[3];
  const float* gw  = (const float*)d_in[4];
  const float* rw  = (const float*)d_in[5];
  const float* sw  = (const float*)d_in[6];
  const float* e1w = (const float*)d_in[7];
  const float* e1b = (const float*)d_in[8];
  const float* e2w = (const float*)d_in[9];
  const float* e2b = (const float*)d_in[10];
  float* out = (float*)d_out;
  char* ws = (char*)d_ws;

  // adaptive chunking: pick fewest chunks whose buffers fit ws_size
  const size_t fixedW = 1060864;
  int TCc = 0, xpb = 0;
  for (int c = 1; c <= 6; c++){
    int tcc = (((TF + c - 1)/c) + 63) & ~63;
    int xp  = tcc + 3264;
    size_t need = fixedW + 2*(size_t)xp*1024 + (size_t)NL*512*(size_t)tcc*2;
    if (need <= ws_size){ TCc = tcc; xpb = xp; break; }
  }
  if (!TCc){ TCc = 2240; xpb = 2240 + 3264; }   // 81.5 MB, always fits

  f16* wsk   = (f16*)(ws);                      //   491,520
  f16* e1f   = (f16*)(ws +   491520);           //   131,072
  f16* e2f   = (f16*)(ws +   622592);           //   131,072
  f16* fgpf  = (f16*)(ws +  753664);            //   122,880
  f16* ggpf  = (f16*)(ws +  876544);            //   122,880
  u32* rwp   = (u32*)(ws +  999424);            //    61,440
  f16* xpA   = (f16*)(ws + fixedW);
  f16* xpB   = (f16*)(ws + fixedW + (size_t)xpb*1024);
  f16* zstack = (f16*)(ws + fixedW + 2*(size_t)xpb*1024);

  int S[NL+1]; S[NL] = 0;
  for (int i = NL-1; i >= 0; i--) S[i] = S[i+1] + (1 << (i % 10));

  prep3<<<dim3(484), 256, 0, stream>>>(sw, e1w, e2w, fw, gw, rw,
                                       wsk, e1f, e2f, fgpf, ggpf, rwp);

  f16* bufs[2] = {xpA, xpB};
  for (int tc0 = 0; tc0 < TF; tc0 += TCc){
    int TcAct = TF - tc0; if (TcAct > TCc) TcAct = TCc;
    int cur = 0;
    for (int s = 0; s < 3; s++){
      int g0 = s*10;
      Trim7 tr;
      for (int li = 0; li < 7; li++) tr.t[li] = S[g0+li+1];
      int Lfinal = TcAct + S[g0+7];
      const f16* gin = (s == 0) ? (const f16*)nullptr : bufs[cur];
      const float* yArg = (s == 0) ? y : (const float*)nullptr;
      int nxt = (s == 0) ? 0 : (cur ^ 1);
      group7m<<<dim3((Lfinal + WGRP-1)/WGRP, NB), 256, 0, stream>>>(
          gin, yArg, cw, cb, tc0, bufs[nxt], zstack, g0, Lfinal, TcAct,
          TCc, xpb, fgpf, ggpf, rwp, tr);
      cur = nxt;
      for (int i = g0+7; i <= g0+9; i++){
        int d = 1 << (i % 10);
        int Tout = TcAct + S[i+1];
        singlem<<<dim3((Tout + 127)/128, NB), 256, 0, stream>>>(
            bufs[cur], bufs[cur^1], zstack + (size_t)i*512*TCc,
            fgpf + (size_t)i*2048, ggpf + (size_t)i*2048, rwp + (size_t)i*512,
            Tout, d, S[i+1], TcAct, TCc, xpb);
        cur ^= 1;
      }
    }
    skipend<<<dim3((TcAct + 63)/64, NB), 512, 0, stream>>>(
        zstack, wsk, e1f, e1b, e2f, e2b, out, tc0, TcAct, TCc);
  }
}